// Round 8
// baseline (694.950 us; speedup 1.0000x reference)
//
#include <hip/hip_runtime.h>
#include <hip/hip_cooperative_groups.h>
#include <stdint.h>

namespace cg = cooperative_groups;

// SuperpointGenerator v7: one cooperative kernel (GRID=256 = 1 block/CU,
// guaranteed co-resident) with runtime fallback to the verified v5
// 8-kernel pipeline if hipLaunchCooperativeKernel errors.
// R7 theory: v6's failure was a swallowed cooperative-launch error at
// GRID=512 (needs 2 blocks/CU). 256 blocks x 512 thr with
// __launch_bounds__(512,2) cannot be TooLarge.

#define BATCHES 32
#define NPTS    (1 << 18)
#define MAX_SP  512
#define NBUK    76
#define BUK_VOX 16384
#define DRANGE  (NBUK * BUK_VOX)     // 1245184
#define OFFSET  (DRANGE / 2)
#define DWORDS  (DRANGE / 4)
#define BUK_DW  (BUK_VOX / 4)        // 4096
#define TIERCAP 18432
#define GRID    256                  // 1 block/CU — co-residency guaranteed
#define TPB     512
#define SUBB    (GRID / BATCHES)     // 8 sub-blocks per batch
#define PPB     (NPTS / SUBB)        // 32768 points per sub-block
#define PPT     (PPB / TPB)          // 64 points per thread

typedef uint32_t u32x4 __attribute__((ext_vector_type(4)));

struct WS {
    uint32_t* dense; int* vidx; int* lists; int* blkcnt; int* blkbase;
    int* bukbase; int* buktot; int* bhist; int* params; int* wbase; int* tbase;
    uint32_t* wid; int* wcnt; uint32_t* tier; uint32_t* lookup; int* counters;
};

__device__ __forceinline__ int point_idx_nt(const float* __restrict__ c3) {
    float x = __builtin_nontemporal_load(c3 + 0);
    float y = __builtin_nontemporal_load(c3 + 1);
    float z = __builtin_nontemporal_load(c3 + 2);
    int vx = (int)(x / 0.2f);        // IEEE f32 divide + trunc-to-zero == ref
    int vy = (int)(y / 0.2f);
    int vz = (int)(z / 0.2f);
    int id = vx * 10000 + vy * 100 + vz;
    int idx = id + OFFSET;
    idx = idx < 0 ? 0 : (idx >= DRANGE ? DRANGE - 1 : idx);  // memory safety only
    return idx;
}

// ======================= cooperative all-in-one =======================
__global__ void __launch_bounds__(TPB, 2) superpoint_all(
    const float* __restrict__ coords, WS w, int* __restrict__ out)
{
    __shared__ union {
        struct { int cnt[NBUK]; } p1;                                 // P1/P3
        struct { int c[SUBB * NBUK]; int start[NBUK]; } p2;
        struct { uint32_t cnt[BUK_DW]; uint32_t h8[8 * 256]; } p4;    // 24 KB
        struct { int tot[256]; int wcb[NBUK]; int tcb[NBUK]; } p5;
        struct { int wpos; int tl[TPB]; } p6;
        struct { uint32_t wu[MAX_SP]; int wc[MAX_SP]; } p7;
        struct { uint32_t lu[MAX_SP]; } p8;
    } sh;

    cg::grid_group grid = cg::this_grid();
    int g = blockIdx.x, tid = threadIdx.x;
    int b = g >> 3, s = g & (SUBB - 1);

    // ---- P1: vidx + per-(block,bucket) counts ----
    if (tid < NBUK) sh.p1.cnt[tid] = 0;
    __syncthreads();
    {
        size_t base = (size_t)b * NPTS + (size_t)s * PPB;
        #pragma unroll 4
        for (int j = 0; j < PPT; ++j) {
            size_t pt = base + j * TPB + tid;
            int idx = point_idx_nt(coords + pt * 3);
            __builtin_nontemporal_store(idx, &w.vidx[pt]);
            atomicAdd(&sh.p1.cnt[idx >> 14], 1);
        }
    }
    __syncthreads();
    if (tid < NBUK) w.blkcnt[g * NBUK + tid] = sh.p1.cnt[tid];
    grid.sync();

    // ---- P2: per-batch scan -> bases ----
    if (g < BATCHES) {
        for (int i = tid; i < SUBB * NBUK; i += TPB)
            sh.p2.c[i] = w.blkcnt[g * SUBB * NBUK + i];
        __syncthreads();
        if (tid < NBUK) {
            int t = 0;
            for (int s2 = 0; s2 < SUBB; ++s2) t += sh.p2.c[s2 * NBUK + tid];
            w.buktot[g * NBUK + tid] = t;
            sh.p2.start[tid] = t;
        }
        __syncthreads();
        if (tid == 0) {
            int run = 0;
            for (int k = 0; k < NBUK; ++k) { int t = sh.p2.start[k]; sh.p2.start[k] = run; run += t; }
        }
        __syncthreads();
        if (tid < NBUK) {
            int run = sh.p2.start[tid];
            w.bukbase[g * NBUK + tid] = run;
            for (int s2 = 0; s2 < SUBB; ++s2) {
                w.blkbase[(g * SUBB + s2) * NBUK + tid] = run;
                run += sh.p2.c[s2 * NBUK + tid];
            }
        }
    }
    grid.sync();

    // ---- P3: scatter vidx into bucket lists ----
    if (tid < NBUK) sh.p1.cnt[tid] = w.blkbase[g * NBUK + tid];
    __syncthreads();
    {
        size_t base = (size_t)b * NPTS + (size_t)s * PPB;
        #pragma unroll 4
        for (int j = 0; j < PPT; ++j) {
            size_t pt = base + j * TPB + tid;
            int idx = w.vidx[pt];
            int pos = atomicAdd(&sh.p1.cnt[idx >> 14], 1);
            __builtin_nontemporal_store(idx, &w.lists[(size_t)b * NPTS + pos]);
        }
    }
    grid.sync();

    // ---- P4: per-bucket LDS byte count -> dense + hist ----
    for (int t = g; t < BATCHES * NBUK; t += GRID) {
        int b4 = t / NBUK, k = t - b4 * NBUK;
        for (int i = tid; i < BUK_DW; i += TPB) sh.p4.cnt[i] = 0;
        for (int i = tid; i < 8 * 256; i += TPB) sh.p4.h8[i] = 0;
        __syncthreads();
        int st = w.bukbase[b4 * NBUK + k], n = w.buktot[b4 * NBUK + k];
        const int* seg = w.lists + (size_t)b4 * NPTS + st;
        for (int i = tid; i < n; i += TPB) {
            int idx = seg[i] & (BUK_VOX - 1);
            atomicAdd(&sh.p4.cnt[idx >> 2], 1u << ((idx & 3) * 8));
        }
        __syncthreads();
        int rep = (tid >> 6) & 7;
        uint32_t* dw = w.dense + (size_t)b4 * DWORDS + (size_t)k * BUK_DW;
        for (int i = tid; i < BUK_DW; i += TPB) {
            uint32_t wd = sh.p4.cnt[i];
            __builtin_nontemporal_store(wd, &dw[i]);
            if (wd) {
                #pragma unroll
                for (int j = 0; j < 4; ++j) {
                    uint32_t cc = (wd >> (j * 8)) & 255u;
                    if (cc) atomicAdd(&sh.p4.h8[rep * 256 + cc], 1u);
                }
            }
        }
        __syncthreads();
        if (tid < 256) {
            uint32_t ssum = 0;
            #pragma unroll
            for (int r = 0; r < 8; ++r) ssum += sh.p4.h8[r * 256 + tid];
            w.bhist[((size_t)b4 * NBUK + k) * 256 + tid] = (int)ssum;
        }
        __syncthreads();
    }
    grid.sync();

    // ---- P5: T/A/m/nu + winner/tier bases ----
    if (g < BATCHES) {
        if (tid < 256) {
            int ssum = 0;
            for (int k = 0; k < NBUK; ++k) ssum += w.bhist[((size_t)g * NBUK + k) * 256 + tid];
            sh.p5.tot[tid] = ssum;
        }
        __syncthreads();
        if (tid == 0) {
            int nu = 0;
            for (int c = 1; c < 256; ++c) nu += sh.p5.tot[c];
            int acc = 0, c = 255;
            while (c > 1 && acc + sh.p5.tot[c] < MAX_SP) { acc += sh.p5.tot[c]; --c; }
            int T = c, A = acc;
            int m = MAX_SP - A; if (m > sh.p5.tot[T]) m = sh.p5.tot[T];
            w.params[g * 8 + 0] = T;  w.params[g * 8 + 1] = A;
            w.params[g * 8 + 2] = m;  w.params[g * 8 + 3] = nu;
            w.params[g * 8 + 4] = A + m;                   // nw = min(512, nu)
        }
        __syncthreads();
        int T = w.params[g * 8 + 0];
        if (tid < NBUK) {
            int wsum = 0;
            const int* bh = w.bhist + ((size_t)g * NBUK + tid) * 256;
            for (int c = T + 1; c < 256; ++c) wsum += bh[c];
            sh.p5.wcb[tid] = wsum;
            sh.p5.tcb[tid] = bh[T];
        }
        __syncthreads();
        if (tid == 0) {
            int aw = 0, at = 0;
            for (int k = 0; k < NBUK; ++k) {
                w.wbase[g * NBUK + k] = aw; w.tbase[g * NBUK + k] = at;
                aw += sh.p5.wcb[k]; at += sh.p5.tcb[k];
            }
        }
    }
    grid.sync();

    // ---- P6: collect winners + id-ordered tier ----
    for (int t = g; t < BATCHES * NBUK; t += GRID) {
        int b6 = t / NBUK, k = t - b6 * NBUK;
        int T = w.params[b6 * 8 + 0], m = w.params[b6 * 8 + 2];
        int wb = w.wbase[b6 * NBUK + k], tb = w.tbase[b6 * NBUK + k];
        if (tid == 0) sh.p6.wpos = 0;
        __syncthreads();
        const u32x4* dwb = (const u32x4*)(w.dense + (size_t)b6 * DWORDS + (size_t)k * BUK_DW);
        u32x4 v[2];
        v[0] = __builtin_nontemporal_load(&dwb[tid * 2 + 0]);
        v[1] = __builtin_nontemporal_load(&dwb[tid * 2 + 1]);
        int base_id = (k * BUK_DW + tid * 8) * 4;
        int ntier = 0;
        #pragma unroll
        for (int q = 0; q < 2; ++q) {
            #pragma unroll
            for (int d = 0; d < 4; ++d) {
                uint32_t wd = v[q][d];
                if (!wd) continue;
                #pragma unroll
                for (int j = 0; j < 4; ++j) {
                    int c = (int)((wd >> (j * 8)) & 255u);
                    if (c > T) {
                        int pw = atomicAdd(&sh.p6.wpos, 1);
                        w.wid [b6 * MAX_SP + wb + pw] = (uint32_t)(base_id + (q * 4 + d) * 4 + j);
                        w.wcnt[b6 * MAX_SP + wb + pw] = c;
                    } else if (c == T) ++ntier;
                }
            }
        }
        sh.p6.tl[tid] = ntier;
        __syncthreads();
        if (tb < m && ntier > 0) {
            int pre = 0;
            for (int j = 0; j < TPB; ++j) { int tv = sh.p6.tl[j]; if (j < tid) pre += tv; }
            int pos = tb + pre, kk = 0;
            #pragma unroll
            for (int q = 0; q < 2; ++q) {
                #pragma unroll
                for (int d = 0; d < 4; ++d) {
                    uint32_t wd = v[q][d];
                    if (!wd) continue;
                    #pragma unroll
                    for (int j = 0; j < 4; ++j) {
                        int c = (int)((wd >> (j * 8)) & 255u);
                        if (c == T) {
                            int q2 = pos + kk; ++kk;
                            if (q2 < TIERCAP) w.tier[b6 * TIERCAP + q2] = (uint32_t)(base_id + (q * 4 + d) * 4 + j);
                        }
                    }
                }
            }
        }
        __syncthreads();
    }
    grid.sync();

    // ---- P7: rank 512 by (count desc, id asc) ----
    if (g < BATCHES) {
        int T = w.params[g * 8 + 0], A = w.params[g * 8 + 1];
        int nu = w.params[g * 8 + 3], nw = w.params[g * 8 + 4];
        if (tid < A)       { sh.p7.wu[tid] = w.wid[g * MAX_SP + tid]; sh.p7.wc[tid] = w.wcnt[g * MAX_SP + tid]; }
        else if (tid < nw) { sh.p7.wu[tid] = w.tier[g * TIERCAP + (tid - A)]; sh.p7.wc[tid] = T; }
        __syncthreads();
        if (tid < nw) {
            uint32_t u = sh.p7.wu[tid]; int c = sh.p7.wc[tid];
            int r = 0, ur = 0;
            for (int j = 0; j < nw; ++j) {
                uint32_t uj = sh.p7.wu[j]; int cj = sh.p7.wc[j];
                r  += ((cj > c) || (cj == c && uj < u)) ? 1 : 0;
                ur += (uj < u) ? 1 : 0;
            }
            int label = (nu <= MAX_SP) ? ur : r;           // inverse branch: id-rank
            w.lookup[g * MAX_SP + ur] = (u << 9) | (uint32_t)label;
        }
    }
    grid.sync();

    // ---- P8: binary-search labels ----
    sh.p8.lu[tid] = w.lookup[b * MAX_SP + tid];
    __syncthreads();
    {
        int nw = w.params[b * 8 + 4];
        size_t base = (size_t)b * NPTS + (size_t)s * PPB;
        #pragma unroll 4
        for (int j = 0; j < PPT; ++j) {
            size_t pt = base + j * TPB + tid;
            uint32_t u = (uint32_t)__builtin_nontemporal_load(&w.vidx[pt]);
            int lo = 0, hi = nw;
            while (lo < hi) { int mid = (lo + hi) >> 1; if ((sh.p8.lu[mid] >> 9) < u) lo = mid + 1; else hi = mid; }
            int label = 0;
            if (lo < nw && (sh.p8.lu[lo] >> 9) == u) label = (int)(sh.p8.lu[lo] & 511u);
            __builtin_nontemporal_store(label, &out[pt]);
        }
    }
}

// ======================= v5 fallback kernels (verified) =======================
__global__ void __launch_bounds__(1024) compute_vidx_count(
    const float* __restrict__ coords, int* __restrict__ vidx, int* __restrict__ blkcnt)
{
    int b = blockIdx.x >> 8, blk = blockIdx.x & 255, tid = threadIdx.x;
    __shared__ int cnt[NBUK];
    if (tid < NBUK) cnt[tid] = 0;
    __syncthreads();
    size_t pt = (size_t)b * NPTS + blk * 1024 + tid;
    int idx = point_idx_nt(coords + pt * 3);
    __builtin_nontemporal_store(idx, &vidx[pt]);
    atomicAdd(&cnt[idx >> 14], 1);
    __syncthreads();
    if (tid < NBUK) blkcnt[((size_t)b * 256 + blk) * NBUK + tid] = cnt[tid];
}

__global__ void __launch_bounds__(128) scan_buckets(
    const int* __restrict__ blkcnt, int* __restrict__ blkbase, int* __restrict__ buktot)
{
    int b = blockIdx.x, tid = threadIdx.x;
    __shared__ int c[256 * NBUK];
    __shared__ int start[NBUK];
    for (int i = tid; i < 256 * NBUK; i += 128) c[i] = blkcnt[(size_t)b * 256 * NBUK + i];
    __syncthreads();
    if (tid < NBUK) {
        int s = 0;
        for (int blk = 0; blk < 256; ++blk) s += c[blk * NBUK + tid];
        buktot[b * NBUK + tid] = s;
        start[tid] = s;
    }
    __syncthreads();
    if (tid == 0) {
        int run = 0;
        for (int k = 0; k < NBUK; ++k) { int t = start[k]; start[k] = run; run += t; }
    }
    __syncthreads();
    if (tid < NBUK) {
        int run = start[tid];
        for (int blk = 0; blk < 256; ++blk) {
            size_t o = ((size_t)b * 256 + blk) * NBUK + tid;
            blkbase[o] = run;
            run += c[blk * NBUK + tid];
        }
    }
}

__global__ void __launch_bounds__(1024) scatter_lists(
    const int* __restrict__ vidx, const int* __restrict__ blkbase, int* __restrict__ lists)
{
    int b = blockIdx.x >> 8, blk = blockIdx.x & 255, tid = threadIdx.x;
    __shared__ int pos[NBUK];
    if (tid < NBUK) pos[tid] = blkbase[((size_t)b * 256 + blk) * NBUK + tid];
    __syncthreads();
    size_t pt = (size_t)b * NPTS + blk * 1024 + tid;
    int idx = __builtin_nontemporal_load(&vidx[pt]);
    int p = atomicAdd(&pos[idx >> 14], 1);
    __builtin_nontemporal_store(idx, &lists[(size_t)b * NPTS + p]);
}

__global__ void __launch_bounds__(1024) count_bucket(
    const int* __restrict__ lists, const int* __restrict__ blkbase,
    const int* __restrict__ buktot, uint32_t* __restrict__ dense, int* __restrict__ blockhist)
{
    int k = blockIdx.x, b = blockIdx.y, tid = threadIdx.x;
    __shared__ uint32_t cnt[BUK_DW];
    __shared__ uint32_t h16[16 * 256];
    for (int i = tid; i < BUK_DW; i += 1024) cnt[i] = 0;
    for (int i = tid; i < 16 * 256; i += 1024) h16[i] = 0;
    __syncthreads();
    int start = blkbase[(size_t)b * 256 * NBUK + k];
    int n = buktot[b * NBUK + k];
    const int* seg = lists + (size_t)b * NPTS + start;
    for (int i = tid; i < n; i += 1024) {
        int idx = seg[i] & (BUK_VOX - 1);
        atomicAdd(&cnt[idx >> 2], 1u << ((idx & 3) * 8));
    }
    __syncthreads();
    int rep = tid >> 6;
    uint32_t* dw = dense + (size_t)b * DWORDS + (size_t)k * BUK_DW;
    for (int i = tid; i < BUK_DW; i += 1024) {
        uint32_t w = cnt[i];
        __builtin_nontemporal_store(w, &dw[i]);
        if (w) {
            #pragma unroll
            for (int j = 0; j < 4; ++j) {
                uint32_t cc = (w >> (j * 8)) & 255u;
                if (cc) atomicAdd(&h16[rep * 256 + cc], 1u);
            }
        }
    }
    __syncthreads();
    if (tid < 256) {
        uint32_t s = 0;
        #pragma unroll
        for (int r = 0; r < 16; ++r) s += h16[r * 256 + tid];
        blockhist[((size_t)b * NBUK + k) * 256 + tid] = (int)s;
    }
}

__global__ void __launch_bounds__(256) select_params(
    const int* __restrict__ blockhist, int* __restrict__ params,
    int* __restrict__ wbase, int* __restrict__ tbase)
{
    int b = blockIdx.x, tid = threadIdx.x;
    __shared__ int tot[256];
    __shared__ int wc_[NBUK], tc_[NBUK];
    __shared__ int sh_T;
    int s = 0;
    for (int k = 0; k < NBUK; ++k) s += blockhist[((size_t)b * NBUK + k) * 256 + tid];
    tot[tid] = s;
    __syncthreads();
    if (tid == 0) {
        int nu = 0;
        for (int c = 1; c < 256; ++c) nu += tot[c];
        int acc = 0, c = 255;
        while (c > 1 && acc + tot[c] < MAX_SP) { acc += tot[c]; --c; }
        int T = c, A = acc;
        int m = MAX_SP - A; if (m > tot[T]) m = tot[T];
        params[b * 8 + 0] = T;  params[b * 8 + 1] = A;
        params[b * 8 + 2] = m;  params[b * 8 + 3] = nu;
        params[b * 8 + 4] = A + m;
        sh_T = T;
    }
    __syncthreads();
    int T = sh_T;
    if (tid < NBUK) {
        int ws = 0;
        const int* bh = blockhist + ((size_t)b * NBUK + tid) * 256;
        for (int c = T + 1; c < 256; ++c) ws += bh[c];
        wc_[tid] = ws;
        tc_[tid] = bh[T];
    }
    __syncthreads();
    if (tid == 0) {
        int aw = 0, at = 0;
        for (int k = 0; k < NBUK; ++k) {
            wbase[b * NBUK + k] = aw; tbase[b * NBUK + k] = at;
            aw += wc_[k]; at += tc_[k];
        }
    }
}

__global__ void __launch_bounds__(256) collect(
    const uint32_t* __restrict__ dense, const int* __restrict__ params,
    const int* __restrict__ wbase, const int* __restrict__ tbase,
    uint32_t* __restrict__ wid, int* __restrict__ wcnt, uint32_t* __restrict__ tier)
{
    int k = blockIdx.x, b = blockIdx.y, tid = threadIdx.x;
    int T = params[b * 8 + 0], m = params[b * 8 + 2];
    int wb = wbase[b * NBUK + k], tb = tbase[b * NBUK + k];
    __shared__ int wpos;
    __shared__ int tl[256];
    if (tid == 0) wpos = 0;
    __syncthreads();
    const u32x4* dwb = (const u32x4*)(dense + (size_t)b * DWORDS + (size_t)k * BUK_DW);
    u32x4 v[4];
    #pragma unroll
    for (int q = 0; q < 4; ++q) v[q] = __builtin_nontemporal_load(&dwb[tid * 4 + q]);
    int base_id = (k * BUK_DW + tid * 16) * 4;
    int ntier = 0;
    #pragma unroll
    for (int q = 0; q < 4; ++q) {
        #pragma unroll
        for (int d = 0; d < 4; ++d) {
            uint32_t w = v[q][d];
            if (!w) continue;
            #pragma unroll
            for (int j = 0; j < 4; ++j) {
                int c = (int)((w >> (j * 8)) & 255u);
                if (c > T) {
                    int p = atomicAdd(&wpos, 1);
                    wid [b * MAX_SP + wb + p] = (uint32_t)(base_id + (q * 4 + d) * 4 + j);
                    wcnt[b * MAX_SP + wb + p] = c;
                } else if (c == T) ++ntier;
            }
        }
    }
    tl[tid] = ntier;
    __syncthreads();
    if (tb < m && ntier > 0) {
        int pre = 0;
        for (int j = 0; j < 256; ++j) { int t = tl[j]; if (j < tid) pre += t; }
        int pos = tb + pre, kk = 0;
        #pragma unroll
        for (int q = 0; q < 4; ++q) {
            #pragma unroll
            for (int d = 0; d < 4; ++d) {
                uint32_t w = v[q][d];
                if (!w) continue;
                #pragma unroll
                for (int j = 0; j < 4; ++j) {
                    int c = (int)((w >> (j * 8)) & 255u);
                    if (c == T) {
                        int qq = pos + kk; ++kk;
                        if (qq < TIERCAP) tier[b * TIERCAP + qq] = (uint32_t)(base_id + (q * 4 + d) * 4 + j);
                    }
                }
            }
        }
    }
}

__global__ void __launch_bounds__(512) rank512(
    const int* __restrict__ params, const uint32_t* __restrict__ wid,
    const int* __restrict__ wcnt, const uint32_t* __restrict__ tier,
    uint32_t* __restrict__ lookup, int* __restrict__ counters)
{
    int b = blockIdx.x, tid = threadIdx.x;
    int T = params[b * 8 + 0], A = params[b * 8 + 1];
    int nu = params[b * 8 + 3], nw = params[b * 8 + 4];
    __shared__ uint32_t wu[MAX_SP];
    __shared__ int      wc[MAX_SP];
    if (tid < A)       { wu[tid] = wid[b * MAX_SP + tid]; wc[tid] = wcnt[b * MAX_SP + tid]; }
    else if (tid < nw) { wu[tid] = tier[b * TIERCAP + (tid - A)]; wc[tid] = T; }
    __syncthreads();
    if (tid < nw) {
        uint32_t u = wu[tid]; int c = wc[tid];
        int r = 0, ur = 0;
        for (int j = 0; j < nw; ++j) {
            uint32_t uj = wu[j]; int cj = wc[j];
            r  += ((cj > c) || (cj == c && uj < u)) ? 1 : 0;
            ur += (uj < u) ? 1 : 0;
        }
        int label = (nu <= MAX_SP) ? ur : r;
        lookup[b * MAX_SP + ur] = (u << 9) | (uint32_t)label;
    }
    if (tid == 0) counters[b] = nw;
}

__global__ void __launch_bounds__(256) write_labels(
    const int* __restrict__ vidx, const int* __restrict__ counters,
    const uint32_t* __restrict__ lookup, int* __restrict__ out)
{
    __shared__ uint32_t lu[MAX_SP];
    __shared__ int      sh_nw;
    int b  = blockIdx.x & 31;
    int pt = (blockIdx.x >> 5) * 256 + threadIdx.x;
    if (threadIdx.x == 0) sh_nw = counters[b];
    lu[threadIdx.x]       = lookup[b * MAX_SP + threadIdx.x];
    lu[threadIdx.x + 256] = lookup[b * MAX_SP + threadIdx.x + 256];
    __syncthreads();
    int nw = sh_nw;
    uint32_t u = (uint32_t)__builtin_nontemporal_load(&vidx[(size_t)b * NPTS + pt]);
    int lo = 0, hi = nw;
    while (lo < hi) { int mid = (lo + hi) >> 1; if ((lu[mid] >> 9) < u) lo = mid + 1; else hi = mid; }
    int label = 0;
    if (lo < nw && (lu[lo] >> 9) == u) label = (int)(lu[lo] & 511u);
    __builtin_nontemporal_store(label, &out[(size_t)b * NPTS + pt]);
}

extern "C" void kernel_launch(void* const* d_in, const int* in_sizes, int n_in,
                              void* d_out, int out_size, void* d_ws, size_t ws_size,
                              hipStream_t stream) {
    const float* coords = (const float*)d_in[0];
    int* out = (int*)d_out;

    WS w;
    uint8_t* p = (uint8_t*)d_ws;
    w.dense   = (uint32_t*)p; p += (size_t)BATCHES * DRANGE;            // 39.9 MB
    w.vidx    = (int*)p;      p += (size_t)BATCHES * NPTS * 4;          // 33.6 MB
    w.lists   = (int*)p;      p += (size_t)BATCHES * NPTS * 4;          // 33.6 MB
    w.blkcnt  = (int*)p;      p += (size_t)BATCHES * 256 * NBUK * 4;    // 2.5 MB
    w.blkbase = (int*)p;      p += (size_t)BATCHES * 256 * NBUK * 4;    // 2.5 MB
    w.tier    = (uint32_t*)p; p += (size_t)BATCHES * TIERCAP * 4;       // 2.4 MB
    w.bukbase = (int*)p;      p += (size_t)BATCHES * NBUK * 4;
    w.buktot  = (int*)p;      p += (size_t)BATCHES * NBUK * 4;
    w.wbase   = (int*)p;      p += (size_t)BATCHES * NBUK * 4;
    w.tbase   = (int*)p;      p += (size_t)BATCHES * NBUK * 4;
    w.params  = (int*)p;      p += (size_t)BATCHES * 8 * 4;
    w.wid     = (uint32_t*)p; p += (size_t)BATCHES * MAX_SP * 4;
    w.wcnt    = (int*)p;      p += (size_t)BATCHES * MAX_SP * 4;
    w.counters= (int*)p;      p += (size_t)BATCHES * 4;
    w.lookup  = (uint32_t*)p; p += (size_t)BATCHES * MAX_SP * 4;
    w.bhist   = w.blkcnt;     // alias: blkcnt dead before bhist written (both paths)

    void* kargs[] = { (void*)&coords, (void*)&w, (void*)&out };
    hipError_t err = hipLaunchCooperativeKernel((const void*)superpoint_all,
                                                dim3(GRID), dim3(TPB), kargs, 0, stream);
    if (err != hipSuccess) {
        // deterministic fallback: verified v5 multi-kernel pipeline
        compute_vidx_count<<<BATCHES * 256, 1024, 0, stream>>>(coords, w.vidx, w.blkcnt);
        scan_buckets      <<<BATCHES, 128, 0, stream>>>(w.blkcnt, w.blkbase, w.buktot);
        scatter_lists     <<<BATCHES * 256, 1024, 0, stream>>>(w.vidx, w.blkbase, w.lists);
        count_bucket      <<<dim3(NBUK, BATCHES), 1024, 0, stream>>>(w.lists, w.blkbase, w.buktot, w.dense, w.bhist);
        select_params     <<<BATCHES, 256, 0, stream>>>(w.bhist, w.params, w.wbase, w.tbase);
        collect           <<<dim3(NBUK, BATCHES), 256, 0, stream>>>(w.dense, w.params, w.wbase, w.tbase, w.wid, w.wcnt, w.tier);
        rank512           <<<BATCHES, 512, 0, stream>>>(w.params, w.wid, w.wcnt, w.tier, w.lookup, w.counters);
        write_labels      <<<BATCHES * NPTS / 256, 256, 0, stream>>>(w.vidx, w.counters, w.lookup, out);
    }
}

// Round 9
// 371.329 us; speedup vs baseline: 1.8715x; 1.8715x over previous
//
#include <hip/hip_runtime.h>
#include <stdint.h>

// SuperpointGenerator v9: multi-kernel (coop abandoned — R8: 24% occupancy +
// ~130us coop overhead lost to v5). vs v5: dense[] eliminated (collect
// recounts in LDS, -80 MB), 64 fat blocks/batch (scan64 ~3us, was serial
// scan_buckets), float4/int4 vectorized streams, 4 pts/thread.
// Pipeline:
//   K1 vidx_count   : coords -> vidx + per-(block,bucket) counts
//   K2 scan64       : per-batch prefix -> blkbase/bukbase/buktot
//   K3 scatter4     : vidx -> bucket-segmented lists (LDS cursors)
//   K4 bucket_hist  : per-bucket LDS byte count -> 256-bin histogram only
//   K5 select_params: T, A=#{c>T}, m, per-bucket winner/tier bases
//   K6 collect2     : LDS recount -> winners (c>T) + id-ordered tier (c==T)
//   K7 rank512      : rank by (count desc, id asc) -> packed lookup
//   K8 write_labels4: binary-search packed table, int4 in/out

#define BATCHES 32
#define NPTS    (1 << 18)
#define MAX_SP  512
#define NBUK    76
#define BUK_VOX 16384
#define DRANGE  (NBUK * BUK_VOX)     // 1245184
#define OFFSET  (DRANGE / 2)         // 622592
#define BUK_DW  (BUK_VOX / 4)        // 4096
#define TIERCAP 18432
#define BPB     64                   // blocks per batch in K1/K3/K8
#define PPB     (NPTS / BPB)         // 4096 points per block

typedef float    f32x4 __attribute__((ext_vector_type(4)));
typedef int      i32x4 __attribute__((ext_vector_type(4)));
typedef uint32_t u32x4 __attribute__((ext_vector_type(4)));

__device__ __forceinline__ int pidx(float x, float y, float z) {
    int vx = (int)(x / 0.2f);        // IEEE f32 divide + trunc-to-zero == ref
    int vy = (int)(y / 0.2f);
    int vz = (int)(z / 0.2f);
    int id = vx * 10000 + vy * 100 + vz;
    int idx = id + OFFSET;
    idx = idx < 0 ? 0 : (idx >= DRANGE ? DRANGE - 1 : idx);  // memory safety only
    return idx;
}

// ---- K1: vidx (4 pts/thread, float4 loads) + per-(block,bucket) counts ----
__global__ void __launch_bounds__(1024) vidx_count(
    const float* __restrict__ coords, int* __restrict__ vidx,
    int* __restrict__ blkcnt)
{
    int b = blockIdx.x >> 6, blk = blockIdx.x & 63, tid = threadIdx.x;
    __shared__ int cnt[NBUK];
    if (tid < NBUK) cnt[tid] = 0;
    __syncthreads();
    size_t p0 = (size_t)b * NPTS + (size_t)blk * PPB + (size_t)tid * 4;
    const f32x4* cp = (const f32x4*)(coords + p0 * 3);   // 48 B, 16B-aligned
    f32x4 a = __builtin_nontemporal_load(cp + 0);
    f32x4 c = __builtin_nontemporal_load(cp + 1);
    f32x4 d = __builtin_nontemporal_load(cp + 2);
    i32x4 iv;
    iv[0] = pidx(a[0], a[1], a[2]);
    iv[1] = pidx(a[3], c[0], c[1]);
    iv[2] = pidx(c[2], c[3], d[0]);
    iv[3] = pidx(d[1], d[2], d[3]);
    __builtin_nontemporal_store(iv, (i32x4*)(vidx + p0));
    atomicAdd(&cnt[iv[0] >> 14], 1);
    atomicAdd(&cnt[iv[1] >> 14], 1);
    atomicAdd(&cnt[iv[2] >> 14], 1);
    atomicAdd(&cnt[iv[3] >> 14], 1);
    __syncthreads();
    if (tid < NBUK) blkcnt[blockIdx.x * NBUK + tid] = cnt[tid];
}

// ---- K2: per-batch scan over 64 blocks -> bases ----
__global__ void __launch_bounds__(128) scan64(
    const int* __restrict__ blkcnt, int* __restrict__ blkbase,
    int* __restrict__ bukbase, int* __restrict__ buktot)
{
    int b = blockIdx.x, tid = threadIdx.x;
    __shared__ int c[BPB * NBUK];    // 19456 B
    __shared__ int start[NBUK];
    for (int i = tid; i < BPB * NBUK; i += 128)
        c[i] = blkcnt[(size_t)b * BPB * NBUK + i];
    __syncthreads();
    if (tid < NBUK) {
        int s = 0;
        for (int blk = 0; blk < BPB; ++blk) s += c[blk * NBUK + tid];
        buktot[b * NBUK + tid] = s;
        start[tid] = s;
    }
    __syncthreads();
    if (tid == 0) {
        int run = 0;
        for (int k = 0; k < NBUK; ++k) { int t = start[k]; start[k] = run; run += t; }
    }
    __syncthreads();
    if (tid < NBUK) {
        int run = start[tid];
        bukbase[b * NBUK + tid] = run;
        for (int blk = 0; blk < BPB; ++blk) {
            blkbase[((size_t)b * BPB + blk) * NBUK + tid] = run;
            run += c[blk * NBUK + tid];
        }
    }
}

// ---- K3: scatter vidx into bucket-segmented lists ----
__global__ void __launch_bounds__(1024) scatter4(
    const int* __restrict__ vidx, const int* __restrict__ blkbase,
    int* __restrict__ lists)
{
    int b = blockIdx.x >> 6, tid = threadIdx.x;
    __shared__ int pos[NBUK];
    if (tid < NBUK) pos[tid] = blkbase[blockIdx.x * NBUK + tid];
    __syncthreads();
    size_t p0 = (size_t)b * NPTS + (size_t)(blockIdx.x & 63) * PPB + (size_t)tid * 4;
    i32x4 iv = __builtin_nontemporal_load((const i32x4*)(vidx + p0));
    int* lb = lists + (size_t)b * NPTS;
    #pragma unroll
    for (int j = 0; j < 4; ++j) {
        int idx = iv[j];
        int p = atomicAdd(&pos[idx >> 14], 1);
        __builtin_nontemporal_store(idx, &lb[p]);
    }
}

// ---- K4: per-(batch,bucket) LDS byte count -> 256-bin histogram ----
__global__ void __launch_bounds__(1024) bucket_hist(
    const int* __restrict__ lists, const int* __restrict__ bukbase,
    const int* __restrict__ buktot, int* __restrict__ bhist)
{
    int k = blockIdx.x, b = blockIdx.y, tid = threadIdx.x;
    __shared__ uint32_t cnt[BUK_DW];     // 16 KB
    __shared__ uint32_t h8[8 * 256];     // 8 KB
    for (int i = tid; i < BUK_DW; i += 1024) cnt[i] = 0;
    for (int i = tid; i < 8 * 256; i += 1024) h8[i] = 0;
    __syncthreads();
    int st = bukbase[b * NBUK + k], n = buktot[b * NBUK + k];
    const int* seg = lists + (size_t)b * NPTS + st;
    for (int i = tid; i < n; i += 1024) {
        int idx = seg[i] & (BUK_VOX - 1);
        atomicAdd(&cnt[idx >> 2], 1u << ((idx & 3) * 8));
    }
    __syncthreads();
    int rep = (tid >> 7) & 7;
    for (int i = tid; i < BUK_DW; i += 1024) {
        uint32_t w = cnt[i];
        if (w) {
            #pragma unroll
            for (int j = 0; j < 4; ++j) {
                uint32_t cc = (w >> (j * 8)) & 255u;
                if (cc) atomicAdd(&h8[rep * 256 + cc], 1u);
            }
        }
    }
    __syncthreads();
    if (tid < 256) {
        uint32_t s = 0;
        #pragma unroll
        for (int r = 0; r < 8; ++r) s += h8[r * 256 + tid];
        bhist[((size_t)b * NBUK + k) * 256 + tid] = (int)s;
    }
}

// ---- K5: derive T/A/m/nu and per-bucket winner/tier exclusive bases ----
__global__ void __launch_bounds__(256) select_params(
    const int* __restrict__ bhist, int* __restrict__ params,
    int* __restrict__ wbase, int* __restrict__ tbase)
{
    int b = blockIdx.x, tid = threadIdx.x;
    __shared__ int tot[256];
    __shared__ int wc_[NBUK], tc_[NBUK];
    __shared__ int sh_T;
    int s = 0;
    for (int k = 0; k < NBUK; ++k) s += bhist[((size_t)b * NBUK + k) * 256 + tid];
    tot[tid] = s;
    __syncthreads();
    if (tid == 0) {
        int nu = 0;
        for (int c = 1; c < 256; ++c) nu += tot[c];
        int acc = 0, c = 255;
        while (c > 1 && acc + tot[c] < MAX_SP) { acc += tot[c]; --c; }
        int T = c, A = acc;
        int m = MAX_SP - A; if (m > tot[T]) m = tot[T];   // nu<=512: whole tier
        params[b * 8 + 0] = T;  params[b * 8 + 1] = A;
        params[b * 8 + 2] = m;  params[b * 8 + 3] = nu;
        params[b * 8 + 4] = A + m;                        // nw = min(512, nu)
        sh_T = T;
    }
    __syncthreads();
    int T = sh_T;
    if (tid < NBUK) {
        int ws = 0;
        const int* bh = bhist + ((size_t)b * NBUK + tid) * 256;
        for (int c = T + 1; c < 256; ++c) ws += bh[c];
        wc_[tid] = ws;
        tc_[tid] = bh[T];
    }
    __syncthreads();
    if (tid == 0) {
        int aw = 0, at = 0;
        for (int k = 0; k < NBUK; ++k) {
            wbase[b * NBUK + k] = aw; tbase[b * NBUK + k] = at;
            aw += wc_[k]; at += tc_[k];
        }
    }
}

// ---- K6: LDS recount -> winners (any order) + tier (exact id order) ----
__global__ void __launch_bounds__(512) collect2(
    const int* __restrict__ lists, const int* __restrict__ bukbase,
    const int* __restrict__ buktot, const int* __restrict__ params,
    const int* __restrict__ wbase, const int* __restrict__ tbase,
    uint32_t* __restrict__ wid, int* __restrict__ wcnt, uint32_t* __restrict__ tier)
{
    int k = blockIdx.x, b = blockIdx.y, tid = threadIdx.x;
    int T = params[b * 8 + 0], m = params[b * 8 + 2];
    int wb = wbase[b * NBUK + k], tb = tbase[b * NBUK + k];
    __shared__ uint32_t cnt[BUK_DW];     // 16 KB
    __shared__ int tl[512];
    __shared__ int wpos;
    for (int i = tid; i < BUK_DW; i += 512) cnt[i] = 0;
    if (tid == 0) wpos = 0;
    __syncthreads();
    int st = bukbase[b * NBUK + k], n = buktot[b * NBUK + k];
    const int* seg = lists + (size_t)b * NPTS + st;
    for (int i = tid; i < n; i += 512) {
        int idx = seg[i] & (BUK_VOX - 1);
        atomicAdd(&cnt[idx >> 2], 1u << ((idx & 3) * 8));
    }
    __syncthreads();
    // per-thread CONTIGUOUS 8 dwords (b128 x2): id order within thread, tid asc
    u32x4 v[2];
    v[0] = ((const u32x4*)cnt)[tid * 2 + 0];
    v[1] = ((const u32x4*)cnt)[tid * 2 + 1];
    int base_id = (k * BUK_DW + tid * 8) * 4;
    int ntier = 0;
    #pragma unroll
    for (int q = 0; q < 2; ++q) {
        #pragma unroll
        for (int d = 0; d < 4; ++d) {
            uint32_t w = v[q][d];
            if (!w) continue;
            #pragma unroll
            for (int j = 0; j < 4; ++j) {
                int c = (int)((w >> (j * 8)) & 255u);
                if (c > T) {
                    int p = atomicAdd(&wpos, 1);
                    wid [b * MAX_SP + wb + p] = (uint32_t)(base_id + (q * 4 + d) * 4 + j);
                    wcnt[b * MAX_SP + wb + p] = c;
                } else if (c == T) ++ntier;
            }
        }
    }
    tl[tid] = ntier;
    __syncthreads();
    if (tb < m && ntier > 0) {           // only blocks that can hold tier[0..m)
        int pre = 0;
        for (int j = 0; j < 512; ++j) { int t = tl[j]; if (j < tid) pre += t; }
        int pos = tb + pre, kk = 0;
        #pragma unroll
        for (int q = 0; q < 2; ++q) {
            #pragma unroll
            for (int d = 0; d < 4; ++d) {
                uint32_t w = v[q][d];
                if (!w) continue;
                #pragma unroll
                for (int j = 0; j < 4; ++j) {
                    int c = (int)((w >> (j * 8)) & 255u);
                    if (c == T) {
                        int q2 = pos + kk; ++kk;
                        if (q2 < TIERCAP) tier[b * TIERCAP + q2] = (uint32_t)(base_id + (q * 4 + d) * 4 + j);
                    }
                }
            }
        }
    }
}

// ---- K7: rank 512 winners; emit PACKED table (idx<<9 | label), sorted by idx ----
__global__ void __launch_bounds__(512) rank512(
    const int* __restrict__ params, const uint32_t* __restrict__ wid,
    const int* __restrict__ wcnt, const uint32_t* __restrict__ tier,
    uint32_t* __restrict__ lookup)
{
    int b = blockIdx.x, tid = threadIdx.x;
    int T = params[b * 8 + 0], A = params[b * 8 + 1];
    int nu = params[b * 8 + 3], nw = params[b * 8 + 4];
    __shared__ uint32_t wu[MAX_SP];
    __shared__ int      wc[MAX_SP];
    if (tid < A)       { wu[tid] = wid[b * MAX_SP + tid]; wc[tid] = wcnt[b * MAX_SP + tid]; }
    else if (tid < nw) { wu[tid] = tier[b * TIERCAP + (tid - A)]; wc[tid] = T; }
    __syncthreads();
    if (tid < nw) {
        uint32_t u = wu[tid]; int c = wc[tid];
        int r = 0, ur = 0;
        for (int j = 0; j < nw; ++j) {
            uint32_t uj = wu[j]; int cj = wc[j];
            r  += ((cj > c) || (cj == c && uj < u)) ? 1 : 0;
            ur += (uj < u) ? 1 : 0;
        }
        int label = (nu <= MAX_SP) ? ur : r;               // inverse branch: id-rank
        lookup[b * MAX_SP + ur] = (u << 9) | (uint32_t)label;   // idx 21b | label 9b
    }
}

// ---- K8: label 4 pts/thread via binary search of packed LDS table ----
__global__ void __launch_bounds__(1024) write_labels4(
    const int* __restrict__ vidx, const int* __restrict__ params,
    const uint32_t* __restrict__ lookup, int* __restrict__ out)
{
    __shared__ uint32_t lu[MAX_SP];
    int b = blockIdx.x >> 6, tid = threadIdx.x;
    if (tid < MAX_SP) lu[tid] = lookup[b * MAX_SP + tid];
    __syncthreads();
    int nw = params[b * 8 + 4];
    size_t p0 = (size_t)b * NPTS + (size_t)(blockIdx.x & 63) * PPB + (size_t)tid * 4;
    i32x4 iv = __builtin_nontemporal_load((const i32x4*)(vidx + p0));
    i32x4 ov;
    #pragma unroll
    for (int j = 0; j < 4; ++j) {
        uint32_t u = (uint32_t)iv[j];
        int lo = 0, hi = nw;
        while (lo < hi) { int mid = (lo + hi) >> 1; if ((lu[mid] >> 9) < u) lo = mid + 1; else hi = mid; }
        int label = 0;
        if (lo < nw && (lu[lo] >> 9) == u) label = (int)(lu[lo] & 511u);
        ov[j] = label;
    }
    __builtin_nontemporal_store(ov, (i32x4*)(out + p0));
}

extern "C" void kernel_launch(void* const* d_in, const int* in_sizes, int n_in,
                              void* d_out, int out_size, void* d_ws, size_t ws_size,
                              hipStream_t stream) {
    const float* coords = (const float*)d_in[0];
    int* out = (int*)d_out;

    uint8_t* p = (uint8_t*)d_ws;
    int*      vidx    = (int*)p;      p += (size_t)BATCHES * NPTS * 4;          // 33.6 MB
    int*      lists   = (int*)p;      p += (size_t)BATCHES * NPTS * 4;          // 33.6 MB
    int*      blkcnt  = (int*)p;      p += (size_t)BATCHES * BPB * NBUK * 4;    // 623 KB
    int*      blkbase = (int*)p;      p += (size_t)BATCHES * BPB * NBUK * 4;    // 623 KB
    int*      bhist   = (int*)p;      p += (size_t)BATCHES * NBUK * 256 * 4;    // 2.5 MB
    uint32_t* tier    = (uint32_t*)p; p += (size_t)BATCHES * TIERCAP * 4;       // 2.4 MB
    int*      bukbase = (int*)p;      p += (size_t)BATCHES * NBUK * 4;
    int*      buktot  = (int*)p;      p += (size_t)BATCHES * NBUK * 4;
    int*      wbase   = (int*)p;      p += (size_t)BATCHES * NBUK * 4;
    int*      tbase   = (int*)p;      p += (size_t)BATCHES * NBUK * 4;
    int*      params  = (int*)p;      p += (size_t)BATCHES * 8 * 4;
    uint32_t* wid     = (uint32_t*)p; p += (size_t)BATCHES * MAX_SP * 4;
    int*      wcnt    = (int*)p;      p += (size_t)BATCHES * MAX_SP * 4;
    uint32_t* lookup  = (uint32_t*)p; p += (size_t)BATCHES * MAX_SP * 4;

    vidx_count   <<<BATCHES * BPB, 1024, 0, stream>>>(coords, vidx, blkcnt);
    scan64       <<<BATCHES, 128, 0, stream>>>(blkcnt, blkbase, bukbase, buktot);
    scatter4     <<<BATCHES * BPB, 1024, 0, stream>>>(vidx, blkbase, lists);
    bucket_hist  <<<dim3(NBUK, BATCHES), 1024, 0, stream>>>(lists, bukbase, buktot, bhist);
    select_params<<<BATCHES, 256, 0, stream>>>(bhist, params, wbase, tbase);
    collect2     <<<dim3(NBUK, BATCHES), 512, 0, stream>>>(lists, bukbase, buktot, params, wbase, tbase, wid, wcnt, tier);
    rank512      <<<BATCHES, 512, 0, stream>>>(params, wid, wcnt, tier, lookup);
    write_labels4<<<BATCHES * BPB, 1024, 0, stream>>>(vidx, params, lookup, out);
}